// Round 1
// baseline (182.988 us; speedup 1.0000x reference)
//
#include <hip/hip_runtime.h>

// Sum-reduce along axis 1 of (B, N, 32) f32 -> (B, 32) f32.
// One block per b; thread t owns quad (t&7) of the 32-wide last axis and
// strides rows by 32. Wave reads 64x16B = 1KiB contiguous per iter.
__global__ __launch_bounds__(256, 8) void pacc_reduce_kernel(
    const float* __restrict__ x, float* __restrict__ out, int N) {
    const int b    = blockIdx.x;
    const int t    = threadIdx.x;
    const int quad = t & 7;        // which float4 of the 32-float row
    const int row0 = t >> 3;       // starting row (0..31)
    const int rstr = 256 >> 3;     // 32 rows per pass

    const float4* xb = reinterpret_cast<const float4*>(x) + (size_t)b * N * 8;

    float4 acc = make_float4(0.f, 0.f, 0.f, 0.f);
    for (int r = row0; r < N; r += rstr) {
        float4 v = xb[(size_t)r * 8 + quad];
        acc.x += v.x; acc.y += v.y; acc.z += v.z; acc.w += v.w;
    }

    // Reduce across lanes sharing the same quad (stride 8 within the 64-lane wave).
    #pragma unroll
    for (int m = 8; m < 64; m <<= 1) {
        acc.x += __shfl_xor(acc.x, m, 64);
        acc.y += __shfl_xor(acc.y, m, 64);
        acc.z += __shfl_xor(acc.z, m, 64);
        acc.w += __shfl_xor(acc.w, m, 64);
    }

    __shared__ float4 lds[4][8];
    const int wave = t >> 6;
    const int lane = t & 63;
    if (lane < 8) lds[wave][lane] = acc;
    __syncthreads();

    if (t < 8) {
        float4 s = lds[0][t];
        #pragma unroll
        for (int w = 1; w < 4; ++w) {
            float4 v = lds[w][t];
            s.x += v.x; s.y += v.y; s.z += v.z; s.w += v.w;
        }
        reinterpret_cast<float4*>(out)[(size_t)b * 8 + t] = s;
    }
}

extern "C" void kernel_launch(void* const* d_in, const int* in_sizes, int n_in,
                              void* d_out, int out_size, void* d_ws, size_t ws_size,
                              hipStream_t stream) {
    const float* x = (const float*)d_in[0];
    float* out = (float*)d_out;
    // out_size = B*32 ; in_sizes[0] = B*N*32  =>  N = in_sizes[0] / out_size
    const int B = out_size / 32;
    const int N = in_sizes[0] / out_size;
    pacc_reduce_kernel<<<B, 256, 0, stream>>>(x, out, N);
}

// Round 2
// 159.946 us; speedup vs baseline: 1.1441x; 1.1441x over previous
//
#include <hip/hip_runtime.h>

// Sum-reduce along axis 1 of (B, N, 32) f32 -> (B, 32) f32.
// One block per b; thread t owns quad (t&7) of the 32-wide last axis and
// strides rows by 32. Wave reads 64x16B = 1KiB contiguous per iter.
// Streaming (read-once) input -> nontemporal loads; unrolled pointer walk.

typedef float f32x4 __attribute__((ext_vector_type(4)));

__global__ __launch_bounds__(256, 8) void pacc_reduce_kernel(
    const float* __restrict__ x, float* __restrict__ out, int N) {
    const int b    = blockIdx.x;
    const int t    = threadIdx.x;
    const int quad = t & 7;        // which float4 of the 32-float row
    const int row0 = t >> 3;       // starting row (0..31)
    const int rstr = 32;           // rows per pass (256 threads / 8 quads)

    const f32x4* __restrict__ xb =
        reinterpret_cast<const f32x4*>(x) + (size_t)b * N * 8;
    const f32x4* __restrict__ p = xb + (size_t)row0 * 8 + quad;

    f32x4 acc = {0.f, 0.f, 0.f, 0.f};
    const int iters = (N - row0 + rstr - 1) / rstr;   // 128 for N=4096
    #pragma unroll 8
    for (int i = 0; i < iters; ++i) {
        acc += __builtin_nontemporal_load(p);
        p += rstr * 8;             // 32 rows * 8 quads
    }

    // Reduce across lanes sharing the same quad (stride 8 within the 64-lane wave).
    #pragma unroll
    for (int m = 8; m < 64; m <<= 1) {
        acc.x += __shfl_xor(acc.x, m, 64);
        acc.y += __shfl_xor(acc.y, m, 64);
        acc.z += __shfl_xor(acc.z, m, 64);
        acc.w += __shfl_xor(acc.w, m, 64);
    }

    __shared__ f32x4 lds[4][8];
    const int wave = t >> 6;
    const int lane = t & 63;
    if (lane < 8) lds[wave][lane] = acc;
    __syncthreads();

    if (t < 8) {
        f32x4 s = lds[0][t];
        #pragma unroll
        for (int w = 1; w < 4; ++w) s += lds[w][t];
        reinterpret_cast<f32x4*>(out)[(size_t)b * 8 + t] = s;
    }
}

extern "C" void kernel_launch(void* const* d_in, const int* in_sizes, int n_in,
                              void* d_out, int out_size, void* d_ws, size_t ws_size,
                              hipStream_t stream) {
    const float* x = (const float*)d_in[0];
    float* out = (float*)d_out;
    // out_size = B*32 ; in_sizes[0] = B*N*32  =>  N = in_sizes[0] / out_size
    const int B = out_size / 32;
    const int N = in_sizes[0] / out_size;
    pacc_reduce_kernel<<<B, 256, 0, stream>>>(x, out, N);
}